// Round 4
// baseline (219.595 us; speedup 1.0000x reference)
//
#include <hip/hip_runtime.h>

// WKV (RWKV v4) as a 2-pass chunked parallel scan over T=1024.
// NCH=32 chunks of CHL=32 steps; each thread owns 4 consecutive channels
// (float4 loads/stores). Explicit static double-buffer (separate named
// register arrays, no runtime indexing) + __launch_bounds__(256,2) so the
// compiler keeps 16 float4 loads in flight instead of sinking them.
//
// Kernel A (states): per-chunk local states from identity.
// Kernel B (emit):   prefix-combine chunk states 0..j-1 (batched loads,
//                    L2-resident), then rescan chunk emitting y.

#define T_FIX 1024
#define NCH   32
#define CHL   (T_FIX / NCH)   // 32
#define BATCH 8

__device__ __forceinline__ void wkv_step(float& aa, float& bb, float& pp,
                                         float w, float kt, float vt)
{
    float ww2 = pp + w;
    float q2  = fmaxf(ww2, kt);
    float e1  = __expf(ww2 - q2);
    float e2  = __expf(kt - q2);
    aa = fmaf(e1, aa, e2 * vt);
    bb = fmaf(e1, bb, e2);
    pp = q2;
}

#define F4TOA(a, f) { a[0] = (f).x; a[1] = (f).y; a[2] = (f).z; a[3] = (f).w; }

// ---------------- Kernel A: per-chunk states ----------------
__global__ __launch_bounds__(256, 2)
void wkv_states(const float* __restrict__ td,
                const float* __restrict__ k,
                const float* __restrict__ v,
                float* __restrict__ aa_s,
                float* __restrict__ bb_s,
                float* __restrict__ pp_s,
                int B, int C)
{
    const int C4  = C >> 2;
    int gid = blockIdx.x * blockDim.x + threadIdx.x;
    if (gid >= B * NCH * C4) return;
    int c4  = gid % C4;
    int rem = gid / C4;
    int j   = rem % NCH;
    int b   = rem / NCH;
    int c   = c4 << 2;

    float4 tdv = *(const float4*)(td + c);
    float w[4] = { -__expf(tdv.x), -__expf(tdv.y), -__expf(tdv.z), -__expf(tdv.w) };

    const size_t base = ((size_t)b * T_FIX + (size_t)j * CHL) * C + c;
    const float* kp = k + base;
    const float* vp = v + base;

    float aa[4] = {0.f, 0.f, 0.f, 0.f};
    float bb[4] = {0.f, 0.f, 0.f, 0.f};
    float pp[4] = {-1e38f, -1e38f, -1e38f, -1e38f};

    float4 kb0[BATCH], vb0[BATCH], kb1[BATCH], vb1[BATCH];

    // preload batch 0 -> buf0
    #pragma unroll
    for (int i = 0; i < BATCH; ++i) {
        kb0[i] = *(const float4*)(kp + (size_t)i * C);
        vb0[i] = *(const float4*)(vp + (size_t)i * C);
    }

    // CHL/BATCH = 4 batches; process pairs (buf0, buf1)
    #pragma unroll
    for (int tb = 0; tb < CHL; tb += 2 * BATCH) {
        // prefetch batch tb+BATCH -> buf1
        #pragma unroll
        for (int i = 0; i < BATCH; ++i) {
            kb1[i] = *(const float4*)(kp + (size_t)(tb + BATCH + i) * C);
            vb1[i] = *(const float4*)(vp + (size_t)(tb + BATCH + i) * C);
        }
        // compute buf0
        #pragma unroll
        for (int i = 0; i < BATCH; ++i) {
            float ka[4], va[4];
            F4TOA(ka, kb0[i]); F4TOA(va, vb0[i]);
            #pragma unroll
            for (int cc = 0; cc < 4; ++cc)
                wkv_step(aa[cc], bb[cc], pp[cc], w[cc], ka[cc], va[cc]);
        }
        // prefetch batch tb+2*BATCH -> buf0
        if (tb + 2 * BATCH < CHL) {
            #pragma unroll
            for (int i = 0; i < BATCH; ++i) {
                kb0[i] = *(const float4*)(kp + (size_t)(tb + 2 * BATCH + i) * C);
                vb0[i] = *(const float4*)(vp + (size_t)(tb + 2 * BATCH + i) * C);
            }
        }
        // compute buf1
        #pragma unroll
        for (int i = 0; i < BATCH; ++i) {
            float ka[4], va[4];
            F4TOA(ka, kb1[i]); F4TOA(va, vb1[i]);
            #pragma unroll
            for (int cc = 0; cc < 4; ++cc)
                wkv_step(aa[cc], bb[cc], pp[cc], w[cc], ka[cc], va[cc]);
        }
    }

    size_t sidx = ((size_t)j * B + b) * C + c;
    *(float4*)(aa_s + sidx) = make_float4(aa[0], aa[1], aa[2], aa[3]);
    *(float4*)(bb_s + sidx) = make_float4(bb[0], bb[1], bb[2], bb[3]);
    *(float4*)(pp_s + sidx) = make_float4(pp[0], pp[1], pp[2], pp[3]);
}

// ---------------- Kernel B: prefix combine + emit ----------------
__global__ __launch_bounds__(256, 2)
void wkv_emit(const float* __restrict__ td,
              const float* __restrict__ tf,
              const float* __restrict__ k,
              const float* __restrict__ v,
              const float* __restrict__ aa_s,
              const float* __restrict__ bb_s,
              const float* __restrict__ pp_s,
              float* __restrict__ y,
              int B, int C)
{
    const int C4  = C >> 2;
    int gid = blockIdx.x * blockDim.x + threadIdx.x;
    if (gid >= B * NCH * C4) return;
    int c4  = gid % C4;
    int rem = gid / C4;
    int j   = rem % NCH;   // uniform within a block (C4 % 256 == 0)
    int b   = rem / NCH;
    int c   = c4 << 2;

    float4 tdv = *(const float4*)(td + c);
    float4 tfv = *(const float4*)(tf + c);
    float w[4] = { -__expf(tdv.x), -__expf(tdv.y), -__expf(tdv.z), -__expf(tdv.w) };
    float u[4];  F4TOA(u, tfv);

    float aa[4] = {0.f, 0.f, 0.f, 0.f};
    float bb[4] = {0.f, 0.f, 0.f, 0.f};
    float pp[4] = {-1e38f, -1e38f, -1e38f, -1e38f};

    // ---- prefix combine over chunks 0..j-1, batched by 8 ----
    {
        const size_t BC = (size_t)B * C;
        const size_t s0 = (size_t)b * C + c;
        int jj = 0;
        while (jj + 8 <= j) {
            float4 ca4[8], cb4[8], cm4[8];
            #pragma unroll
            for (int i = 0; i < 8; ++i) {
                size_t sidx = (size_t)(jj + i) * BC + s0;
                ca4[i] = *(const float4*)(aa_s + sidx);
                cb4[i] = *(const float4*)(bb_s + sidx);
                cm4[i] = *(const float4*)(pp_s + sidx);
            }
            #pragma unroll
            for (int i = 0; i < 8; ++i) {
                float ca[4], cb[4], cm[4];
                F4TOA(ca, ca4[i]); F4TOA(cb, cb4[i]); F4TOA(cm, cm4[i]);
                #pragma unroll
                for (int cc = 0; cc < 4; ++cc) {
                    float ppd = pp[cc] + (float)CHL * w[cc];
                    float pn  = fmaxf(ppd, cm[cc]);
                    float ea  = __expf(ppd - pn);
                    float eb  = __expf(cm[cc] - pn);
                    aa[cc] = fmaf(ea, aa[cc], eb * ca[cc]);
                    bb[cc] = fmaf(ea, bb[cc], eb * cb[cc]);
                    pp[cc] = pn;
                }
            }
            jj += 8;
        }
        while (jj < j) {
            size_t sidx = (size_t)jj * BC + s0;
            float4 c_a = *(const float4*)(aa_s + sidx);
            float4 c_b = *(const float4*)(bb_s + sidx);
            float4 c_m = *(const float4*)(pp_s + sidx);
            float ca[4], cb[4], cm[4];
            F4TOA(ca, c_a); F4TOA(cb, c_b); F4TOA(cm, c_m);
            #pragma unroll
            for (int cc = 0; cc < 4; ++cc) {
                float ppd = pp[cc] + (float)CHL * w[cc];
                float pn  = fmaxf(ppd, cm[cc]);
                float ea  = __expf(ppd - pn);
                float eb  = __expf(cm[cc] - pn);
                aa[cc] = fmaf(ea, aa[cc], eb * ca[cc]);
                bb[cc] = fmaf(ea, bb[cc], eb * cb[cc]);
                pp[cc] = pn;
            }
            ++jj;
        }
    }

    // ---- rescan chunk with double-buffered loads, emit y ----
    const size_t base = ((size_t)b * T_FIX + (size_t)j * CHL) * C + c;
    const float* kp = k + base;
    const float* vp = v + base;
    float*       yp = y + base;

    float4 kb0[BATCH], vb0[BATCH], kb1[BATCH], vb1[BATCH];

    #pragma unroll
    for (int i = 0; i < BATCH; ++i) {
        kb0[i] = *(const float4*)(kp + (size_t)i * C);
        vb0[i] = *(const float4*)(vp + (size_t)i * C);
    }

    #pragma unroll
    for (int tb = 0; tb < CHL; tb += 2 * BATCH) {
        #pragma unroll
        for (int i = 0; i < BATCH; ++i) {
            kb1[i] = *(const float4*)(kp + (size_t)(tb + BATCH + i) * C);
            vb1[i] = *(const float4*)(vp + (size_t)(tb + BATCH + i) * C);
        }
        #pragma unroll
        for (int i = 0; i < BATCH; ++i) {
            float ka[4], va[4], ya[4];
            F4TOA(ka, kb0[i]); F4TOA(va, vb0[i]);
            #pragma unroll
            for (int cc = 0; cc < 4; ++cc) {
                float ww = u[cc] + ka[cc];
                float q  = fmaxf(pp[cc], ww);
                float e1 = __expf(pp[cc] - q);
                float e2 = __expf(ww - q);
                ya[cc] = __fdividef(fmaf(e1, aa[cc], e2 * va[cc]),
                                    fmaf(e1, bb[cc], e2));
                wkv_step(aa[cc], bb[cc], pp[cc], w[cc], ka[cc], va[cc]);
            }
            *(float4*)(yp + (size_t)(tb + i) * C) = make_float4(ya[0], ya[1], ya[2], ya[3]);
        }
        if (tb + 2 * BATCH < CHL) {
            #pragma unroll
            for (int i = 0; i < BATCH; ++i) {
                kb0[i] = *(const float4*)(kp + (size_t)(tb + 2 * BATCH + i) * C);
                vb0[i] = *(const float4*)(vp + (size_t)(tb + 2 * BATCH + i) * C);
            }
        }
        #pragma unroll
        for (int i = 0; i < BATCH; ++i) {
            float ka[4], va[4], ya[4];
            F4TOA(ka, kb1[i]); F4TOA(va, vb1[i]);
            #pragma unroll
            for (int cc = 0; cc < 4; ++cc) {
                float ww = u[cc] + ka[cc];
                float q  = fmaxf(pp[cc], ww);
                float e1 = __expf(pp[cc] - q);
                float e2 = __expf(ww - q);
                ya[cc] = __fdividef(fmaf(e1, aa[cc], e2 * va[cc]),
                                    fmaf(e1, bb[cc], e2));
                wkv_step(aa[cc], bb[cc], pp[cc], w[cc], ka[cc], va[cc]);
            }
            *(float4*)(yp + (size_t)(tb + BATCH + i) * C) = make_float4(ya[0], ya[1], ya[2], ya[3]);
        }
    }
}

extern "C" void kernel_launch(void* const* d_in, const int* in_sizes, int n_in,
                              void* d_out, int out_size, void* d_ws, size_t ws_size,
                              hipStream_t stream)
{
    const float* td = (const float*)d_in[3];
    const float* tf = (const float*)d_in[4];
    const float* k  = (const float*)d_in[5];
    const float* v  = (const float*)d_in[6];
    float*       y  = (float*)d_out;

    const int C   = in_sizes[3];
    const int BTC = in_sizes[5];
    const int B   = BTC / (T_FIX * C);

    const size_t N = (size_t)B * C * NCH;
    float* aa_s = (float*)d_ws;
    float* bb_s = aa_s + N;
    float* pp_s = bb_s + N;

    const int block   = 256;
    const int threads = B * NCH * (C >> 2);
    const int grid    = (threads + block - 1) / block;

    wkv_states<<<grid, block, 0, stream>>>(td, k, v, aa_s, bb_s, pp_s, B, C);
    wkv_emit  <<<grid, block, 0, stream>>>(td, tf, k, v, aa_s, bb_s, pp_s, y, B, C);
}